// Round 1
// baseline (2227.766 us; speedup 1.0000x reference)
//
#include <hip/hip_runtime.h>
#include <cmath>

namespace {

constexpr int B_ = 2, T_ = 2048, C_ = 1024, H_ = 16;
constexpr float GAMMA_INV = 0.125f;   // 1/GAMMA
constexpr float SCALE = 0.125f;       // 1/sqrt(D), D=64

// ---------------- GEMM: C = A(MxK) @ B(KxN), fp32 row-major ----------------
constexpr int BM = 128, BN = 128, BK = 16;

__global__ __launch_bounds__(256) void gemm_f32(const float* __restrict__ A,
                                                const float* __restrict__ Bm,
                                                float* __restrict__ Cm,
                                                int N, int K) {
  __shared__ float As[BK][BM + 4];
  __shared__ float Bs[BK][BN];
  const int tid = threadIdx.x;
  const int m0 = blockIdx.y * BM, n0 = blockIdx.x * BN;
  const int tr = tid >> 4, tc = tid & 15;   // 16x16 thread grid
  float acc[8][8] = {};
  for (int k0 = 0; k0 < K; k0 += BK) {
    #pragma unroll
    for (int j = 0; j < 2; ++j) {
      int idx = tid + j * 256;             // 0..511 float4 of A tile
      int m = idx >> 2, kq = (idx & 3) * 4;
      float4 av = *(const float4*)&A[(size_t)(m0 + m) * K + k0 + kq];
      As[kq + 0][m] = av.x; As[kq + 1][m] = av.y;
      As[kq + 2][m] = av.z; As[kq + 3][m] = av.w;
    }
    #pragma unroll
    for (int j = 0; j < 2; ++j) {
      int idx = tid + j * 256;             // 0..511 float4 of B tile
      int kk = idx >> 5, nq = (idx & 31) * 4;
      *(float4*)&Bs[kk][nq] = *(const float4*)&Bm[(size_t)(k0 + kk) * N + n0 + nq];
    }
    __syncthreads();
    #pragma unroll
    for (int kk = 0; kk < BK; ++kk) {
      float4 a0 = *(const float4*)&As[kk][tr * 4];
      float4 a1 = *(const float4*)&As[kk][64 + tr * 4];
      float4 b0 = *(const float4*)&Bs[kk][tc * 4];
      float4 b1 = *(const float4*)&Bs[kk][64 + tc * 4];
      float a[8] = {a0.x, a0.y, a0.z, a0.w, a1.x, a1.y, a1.z, a1.w};
      float b[8] = {b0.x, b0.y, b0.z, b0.w, b1.x, b1.y, b1.z, b1.w};
      #pragma unroll
      for (int i = 0; i < 8; ++i)
        #pragma unroll
        for (int j2 = 0; j2 < 8; ++j2) acc[i][j2] += a[i] * b[j2];
    }
    __syncthreads();
  }
  #pragma unroll
  for (int i = 0; i < 8; ++i) {
    int m = m0 + ((i < 4) ? (tr * 4 + i) : (64 + tr * 4 + i - 4));
    float4 c0 = make_float4(acc[i][0], acc[i][1], acc[i][2], acc[i][3]);
    float4 c1 = make_float4(acc[i][4], acc[i][5], acc[i][6], acc[i][7]);
    *(float4*)&Cm[(size_t)m * N + n0 + tc * 4] = c0;
    *(float4*)&Cm[(size_t)m * N + n0 + 64 + tc * 4] = c1;
  }
}

// -------- transform: raw (B,T,2C) -> packed (B,H,T,128) [amp*cos | amp*sin] --------
__global__ __launch_bounds__(256) void qk_transform(const float* __restrict__ raw,
                                                    float* __restrict__ out) {
  const int idx = blockIdx.x * 256 + threadIdx.x;   // over B*T*C
  const int c = idx & (C_ - 1);
  const int bt = idx >> 10;
  const int t = bt & (T_ - 1);
  const int b = bt >> 11;
  const int h = c >> 6, d = c & 63;
  float amp = raw[(size_t)bt * 2048 + c];
  float ph  = raw[(size_t)bt * 2048 + 1024 + c];
  float sp = (amp > 20.f) ? amp : log1pf(expf(amp));
  float qc = sp * cosf(ph);
  float qs = sp * sinf(ph);
  size_t o = ((size_t)((b * H_ + h) * T_ + t)) * 128 + d;
  out[o] = qc;
  out[o + 64] = qs;
}

// -------- flash attention with moire gate, fp32 --------
// Q,K: (B*H, T, 128) packed; V: (B,T,C) layout; O: (B,T,C) layout
__global__ __launch_bounds__(256) void attn_f32(const float* __restrict__ Q,
                                                const float* __restrict__ Kc,
                                                const float* __restrict__ V,
                                                const float* __restrict__ theta,
                                                float* __restrict__ O) {
  const int bh = blockIdx.y;
  const int b = bh >> 4, h = bh & 15;
  const int q0 = blockIdx.x * 32;
  const int tid = threadIdx.x;
  __shared__ float q_s[32][132];
  __shared__ float k_s[32][132];
  __shared__ float v_s[32][64];
  __shared__ float s_s[32][33];
  __shared__ float m_s[32], l_s[32], esc_s[32];
  __shared__ float cq_s[32], sq_s[32], ck_s[32], sk_s[32];

  const float th = theta[h];
  const float4* Qb4 = (const float4*)(Q + ((size_t)bh * T_ + q0) * 128);
  for (int i = tid; i < 32 * 32; i += 256) {
    int r = i >> 5, c4 = (i & 31) * 4;
    *(float4*)&q_s[r][c4] = Qb4[i];
  }
  if (tid < 32) {
    float cid = (float)(q0 + tid) * GAMMA_INV;
    cq_s[tid] = cosf(th * cid); sq_s[tid] = sinf(th * cid);
    m_s[tid] = -INFINITY; l_s[tid] = 0.0f;
  }
  float o_acc[8] = {};
  const int row = tid >> 3, dsub = (tid & 7) * 8;
  const int r_sc = tid >> 3, cb_sc = (tid & 7) * 4;

  const int nkt = (q0 >> 5) + 1;   // causal: key tiles 0..q0/32
  for (int kt = 0; kt < nkt; ++kt) {
    const int k0 = kt * 32;
    __syncthreads();
    const float4* Kb4 = (const float4*)(Kc + ((size_t)bh * T_ + k0) * 128);
    for (int i = tid; i < 32 * 32; i += 256) {
      int r = i >> 5, c4 = (i & 31) * 4;
      *(float4*)&k_s[r][c4] = Kb4[i];
    }
    const float* Vb = V + ((size_t)(b * T_ + k0)) * C_ + h * 64;
    for (int i = tid; i < 32 * 16; i += 256) {
      int r = i >> 4, c4 = (i & 15) * 4;
      *(float4*)&v_s[r][c4] = *(const float4*)&Vb[(size_t)r * C_ + c4];
    }
    if (tid < 32) {
      float cid = (float)(k0 + tid) * GAMMA_INV;
      ck_s[tid] = cosf(th * cid); sk_s[tid] = sinf(th * cid);
    }
    __syncthreads();
    // ---- scores: each thread computes 4 (row r_sc, cols cb_sc..+3) ----
    {
      float av[4] = {0.f, 0.f, 0.f, 0.f};
      const float4* q4  = (const float4*)&q_s[r_sc][0];
      const float4* k40 = (const float4*)&k_s[cb_sc + 0][0];
      const float4* k41 = (const float4*)&k_s[cb_sc + 1][0];
      const float4* k42 = (const float4*)&k_s[cb_sc + 2][0];
      const float4* k43 = (const float4*)&k_s[cb_sc + 3][0];
      #pragma unroll 8
      for (int d4 = 0; d4 < 32; ++d4) {
        float4 qv = q4[d4];
        float4 k0v = k40[d4], k1v = k41[d4], k2v = k42[d4], k3v = k43[d4];
        av[0] += qv.x * k0v.x + qv.y * k0v.y + qv.z * k0v.z + qv.w * k0v.w;
        av[1] += qv.x * k1v.x + qv.y * k1v.y + qv.z * k1v.z + qv.w * k1v.w;
        av[2] += qv.x * k2v.x + qv.y * k2v.y + qv.z * k2v.z + qv.w * k2v.w;
        av[3] += qv.x * k3v.x + qv.y * k3v.y + qv.z * k3v.z + qv.w * k3v.w;
      }
      const int iq = q0 + r_sc;
      const float cr = cq_s[r_sc], sr = sq_s[r_sc];
      #pragma unroll
      for (int cc = 0; cc < 4; ++cc) {
        int c = cb_sc + cc;
        float gate = cr * ck_s[c] + sr * sk_s[c];
        float sc = av[cc] * SCALE * gate;
        s_s[r_sc][c] = (k0 + c <= iq) ? sc : -INFINITY;
      }
    }
    __syncthreads();
    // ---- online softmax update (one thread per row) ----
    if (tid < 32) {
      const int r = tid;
      float mo = m_s[r];
      float tm = mo;
      #pragma unroll
      for (int c = 0; c < 32; ++c) tm = fmaxf(tm, s_s[r][c]);
      float l_add = 0.f;
      #pragma unroll
      for (int c = 0; c < 32; ++c) {
        float p = expf(s_s[r][c] - tm);   // exp(-inf)=0 handles mask
        s_s[r][c] = p; l_add += p;
      }
      float esc = expf(mo - tm);          // first tile: exp(-inf)=0
      l_s[r] = l_s[r] * esc + l_add;
      m_s[r] = tm;
      esc_s[r] = esc;
    }
    __syncthreads();
    // ---- PV accumulate: 8 threads per row, 8 d-components each ----
    {
      const float esc = esc_s[row];
      #pragma unroll
      for (int i2 = 0; i2 < 8; ++i2) o_acc[i2] *= esc;
      #pragma unroll 4
      for (int c = 0; c < 32; ++c) {
        const float p = s_s[row][c];
        const float4 v0 = *(const float4*)&v_s[c][dsub];
        const float4 v1 = *(const float4*)&v_s[c][dsub + 4];
        o_acc[0] += p * v0.x; o_acc[1] += p * v0.y;
        o_acc[2] += p * v0.z; o_acc[3] += p * v0.w;
        o_acc[4] += p * v1.x; o_acc[5] += p * v1.y;
        o_acc[6] += p * v1.z; o_acc[7] += p * v1.w;
      }
    }
  }
  __syncthreads();
  {
    const float linv = 1.0f / l_s[row];
    float* Ob = O + ((size_t)(b * T_ + q0 + row)) * C_ + h * 64 + dsub;
    float4 o0 = make_float4(o_acc[0] * linv, o_acc[1] * linv, o_acc[2] * linv, o_acc[3] * linv);
    float4 o1 = make_float4(o_acc[4] * linv, o_acc[5] * linv, o_acc[6] * linv, o_acc[7] * linv);
    *(float4*)&Ob[0] = o0;
    *(float4*)&Ob[4] = o1;
  }
}

} // namespace

extern "C" void kernel_launch(void* const* d_in, const int* in_sizes, int n_in,
                              void* d_out, int out_size, void* d_ws, size_t ws_size,
                              hipStream_t stream) {
  const float* x  = (const float*)d_in[0];
  const float* Wq = (const float*)d_in[1];
  const float* Wk = (const float*)d_in[2];
  const float* Wv = (const float*)d_in[3];
  const float* Wo = (const float*)d_in[4];
  const float* th = (const float*)d_in[5];
  float* out = (float*)d_out;
  float* ws = (float*)d_ws;

  // workspace layout (floats):
  //   raw  : 8,388,608   (q_raw, then k_raw, then reused as V|O)
  //   Qb   : 8,388,608
  //   Kb   : 8,388,608
  // total 96 MB
  float* raw = ws;
  float* Qb  = ws + 8388608;
  float* Kb  = ws + 16777216;
  float* Vb  = raw;              // reuse after transforms consumed raw
  float* Ob  = raw + 4194304;

  dim3 blk(256);
  gemm_f32<<<dim3(2048 / BN, 4096 / BM), blk, 0, stream>>>(x, Wq, raw, 2048, 1024);
  qk_transform<<<16384, blk, 0, stream>>>(raw, Qb);
  gemm_f32<<<dim3(2048 / BN, 4096 / BM), blk, 0, stream>>>(x, Wk, raw, 2048, 1024);
  qk_transform<<<16384, blk, 0, stream>>>(raw, Kb);
  gemm_f32<<<dim3(1024 / BN, 4096 / BM), blk, 0, stream>>>(x, Wv, Vb, 1024, 1024);
  attn_f32<<<dim3(64, 32), blk, 0, stream>>>(Qb, Kb, Vb, th, Ob);
  gemm_f32<<<dim3(1024 / BN, 4096 / BM), blk, 0, stream>>>(Ob, Wo, out, 1024, 1024);
}

// Round 2
// 1034.275 us; speedup vs baseline: 2.1539x; 2.1539x over previous
//
#include <hip/hip_runtime.h>
#include <cmath>

namespace {

constexpr int B_ = 2, T_ = 2048, C_ = 1024, H_ = 16;
constexpr float GAMMA_INV = 0.125f;   // 1/GAMMA
constexpr float SCALE = 0.125f;       // 1/sqrt(D), D=64

typedef __attribute__((ext_vector_type(8))) short bf16x8;
typedef __attribute__((ext_vector_type(4))) float f32x4;
typedef unsigned short ushort_t;

__device__ __forceinline__ ushort_t f2bf(float x) {
  union { float f; unsigned int u; } v; v.f = x;
  unsigned int r = (v.u + 0x7fffu + ((v.u >> 16) & 1u)) >> 16;
  return (ushort_t)r;
}

__device__ __forceinline__ f32x4 mfma16(bf16x8 a, bf16x8 b, f32x4 c) {
  return __builtin_amdgcn_mfma_f32_16x16x32_bf16(a, b, c, 0, 0, 0);
}

// ---------------- GEMM: C = A(MxK) @ B(KxN), fp32 row-major ----------------
constexpr int BM = 128, BN = 128, BK = 16;

__global__ __launch_bounds__(256) void gemm_f32(const float* __restrict__ A,
                                                const float* __restrict__ Bm,
                                                float* __restrict__ Cm,
                                                int N, int K) {
  __shared__ float As[BK][BM + 4];
  __shared__ float Bs[BK][BN];
  const int tid = threadIdx.x;
  const int m0 = blockIdx.y * BM, n0 = blockIdx.x * BN;
  const int tr = tid >> 4, tc = tid & 15;   // 16x16 thread grid
  float acc[8][8] = {};
  for (int k0 = 0; k0 < K; k0 += BK) {
    #pragma unroll
    for (int j = 0; j < 2; ++j) {
      int idx = tid + j * 256;
      int m = idx >> 2, kq = (idx & 3) * 4;
      float4 av = *(const float4*)&A[(size_t)(m0 + m) * K + k0 + kq];
      As[kq + 0][m] = av.x; As[kq + 1][m] = av.y;
      As[kq + 2][m] = av.z; As[kq + 3][m] = av.w;
    }
    #pragma unroll
    for (int j = 0; j < 2; ++j) {
      int idx = tid + j * 256;
      int kk = idx >> 5, nq = (idx & 31) * 4;
      *(float4*)&Bs[kk][nq] = *(const float4*)&Bm[(size_t)(k0 + kk) * N + n0 + nq];
    }
    __syncthreads();
    #pragma unroll
    for (int kk = 0; kk < BK; ++kk) {
      float4 a0 = *(const float4*)&As[kk][tr * 4];
      float4 a1 = *(const float4*)&As[kk][64 + tr * 4];
      float4 b0 = *(const float4*)&Bs[kk][tc * 4];
      float4 b1 = *(const float4*)&Bs[kk][64 + tc * 4];
      float a[8] = {a0.x, a0.y, a0.z, a0.w, a1.x, a1.y, a1.z, a1.w};
      float b[8] = {b0.x, b0.y, b0.z, b0.w, b1.x, b1.y, b1.z, b1.w};
      #pragma unroll
      for (int i = 0; i < 8; ++i)
        #pragma unroll
        for (int j2 = 0; j2 < 8; ++j2) acc[i][j2] += a[i] * b[j2];
    }
    __syncthreads();
  }
  #pragma unroll
  for (int i = 0; i < 8; ++i) {
    int m = m0 + ((i < 4) ? (tr * 4 + i) : (64 + tr * 4 + i - 4));
    float4 c0 = make_float4(acc[i][0], acc[i][1], acc[i][2], acc[i][3]);
    float4 c1 = make_float4(acc[i][4], acc[i][5], acc[i][6], acc[i][7]);
    *(float4*)&Cm[(size_t)m * N + n0 + tc * 4] = c0;
    *(float4*)&Cm[(size_t)m * N + n0 + 64 + tc * 4] = c1;
  }
}

// -------- transform: raw (B,T,2C) fp32 -> packed (B,H,T,128) bf16 [amp*cos | amp*sin] --------
__global__ __launch_bounds__(256) void qk_transform(const float* __restrict__ raw,
                                                    ushort_t* __restrict__ out) {
  const int idx = blockIdx.x * 256 + threadIdx.x;   // over B*T*C
  const int c = idx & (C_ - 1);
  const int bt = idx >> 10;
  const int t = bt & (T_ - 1);
  const int b = bt >> 11;
  const int h = c >> 6, d = c & 63;
  float amp = raw[(size_t)bt * 2048 + c];
  float ph  = raw[(size_t)bt * 2048 + 1024 + c];
  float sp = (amp > 20.f) ? amp : log1pf(expf(amp));
  float qc = sp * cosf(ph);
  float qs = sp * sinf(ph);
  size_t o = ((size_t)((b * H_ + h) * T_ + t)) * 128 + d;
  out[o] = f2bf(qc);
  out[o + 64] = f2bf(qs);
}

// -------- V (B,T,C) fp32 -> V^T (B,H,64,T) bf16 --------
__global__ __launch_bounds__(256) void v_transpose(const float* __restrict__ V,
                                                   ushort_t* __restrict__ VT) {
  const int bh = blockIdx.y;
  const int b = bh >> 4, h = bh & 15;
  const int t0 = blockIdx.x * 32;
  __shared__ ushort_t lds[32][72];
  const int i = threadIdx.x;
  {
    int r = i >> 3, d0 = (i & 7) * 8;
    const float* src = V + ((size_t)(b * T_) + t0 + r) * C_ + h * 64 + d0;
    float4 a = *(const float4*)src;
    float4 c = *(const float4*)(src + 4);
    lds[r][d0 + 0] = f2bf(a.x); lds[r][d0 + 1] = f2bf(a.y);
    lds[r][d0 + 2] = f2bf(a.z); lds[r][d0 + 3] = f2bf(a.w);
    lds[r][d0 + 4] = f2bf(c.x); lds[r][d0 + 5] = f2bf(c.y);
    lds[r][d0 + 6] = f2bf(c.z); lds[r][d0 + 7] = f2bf(c.w);
  }
  __syncthreads();
  {
    int d = i >> 2, tq = (i & 3) * 8;
    ushort_t tmp[8];
    #pragma unroll
    for (int j = 0; j < 8; ++j) tmp[j] = lds[tq + j][d];
    ulonglong2 pk;
    pk.x = (unsigned long long)tmp[0] | ((unsigned long long)tmp[1] << 16) |
           ((unsigned long long)tmp[2] << 32) | ((unsigned long long)tmp[3] << 48);
    pk.y = (unsigned long long)tmp[4] | ((unsigned long long)tmp[5] << 16) |
           ((unsigned long long)tmp[6] << 32) | ((unsigned long long)tmp[7] << 48);
    *(ulonglong2*)(VT + ((size_t)bh * 64 + d) * T_ + t0 + tq) = pk;
  }
}

// -------- flash attention, bf16 MFMA, moire gate --------
// Q,K: (B*H, T, 128) bf16; VT: (B*H, 64, T) bf16; O: (B,T,C) fp32
__global__ __launch_bounds__(256) void attn_mfma(const ushort_t* __restrict__ Q,
                                                 const ushort_t* __restrict__ K,
                                                 const ushort_t* __restrict__ VT,
                                                 const float* __restrict__ theta,
                                                 float* __restrict__ O) {
  const int bh = blockIdx.y;
  const int b = bh >> 4, h = bh & 15;
  const int wid = threadIdx.x >> 6, lane = threadIdx.x & 63;
  const int q_base = blockIdx.x * 64 + wid * 16;
  const int lr = lane & 15, lg = lane >> 4;
  __shared__ alignas(16) ushort_t p_s[4][16][40];   // per-wave P tile, padded (80B rows)

  const float th = theta[h];

  // Q A-fragments (rows q_base+lr, 4 K-steps of 32 over d=0..127)
  bf16x8 qf[4];
  {
    const ushort_t* Qrow = Q + ((size_t)bh * T_ + q_base + lr) * 128 + lg * 8;
    #pragma unroll
    for (int ks = 0; ks < 4; ++ks) qf[ks] = *(const bf16x8*)(Qrow + ks * 32);
  }

  // row trig (gate rank-2 factors), SCALE folded in
  float cq[4], sq[4];
  #pragma unroll
  for (int r = 0; r < 4; ++r) {
    float ang = th * (float)(q_base + lg * 4 + r) * GAMMA_INV;
    cq[r] = cosf(ang) * SCALE;
    sq[r] = sinf(ang) * SCALE;
  }
  // key trig state for k = lr and k = lr+16; rotated by th*4 per 32-key tile
  float a0 = th * (float)lr * GAMMA_INV;
  float a1 = th * (float)(lr + 16) * GAMMA_INV;
  float ck0 = cosf(a0), sk0 = sinf(a0);
  float ck1 = cosf(a1), sk1 = sinf(a1);
  const float cd = cosf(th * 4.0f), sd = sinf(th * 4.0f);

  f32x4 o_acc[4];
  #pragma unroll
  for (int n = 0; n < 4; ++n)
    #pragma unroll
    for (int r = 0; r < 4; ++r) o_acc[n][r] = 0.0f;
  float m_run[4], l_run[4];
  #pragma unroll
  for (int r = 0; r < 4; ++r) { m_run[r] = -1e30f; l_run[r] = 0.0f; }

  const int nkt = ((q_base + 15) >> 5) + 1;
  for (int kt = 0; kt < nkt; ++kt) {
    const int k0 = kt * 32;
    // ---- S = Q @ K^T (16q x 32k), two 16-col subtiles ----
    f32x4 s0, s1;
    #pragma unroll
    for (int r = 0; r < 4; ++r) { s0[r] = 0.0f; s1[r] = 0.0f; }
    {
      const ushort_t* Krow0 = K + ((size_t)bh * T_ + k0 + lr) * 128 + lg * 8;
      const ushort_t* Krow1 = Krow0 + 16 * 128;
      #pragma unroll
      for (int ks = 0; ks < 4; ++ks) {
        bf16x8 kf0 = *(const bf16x8*)(Krow0 + ks * 32);
        bf16x8 kf1 = *(const bf16x8*)(Krow1 + ks * 32);
        s0 = mfma16(qf[ks], kf0, s0);
        s1 = mfma16(qf[ks], kf1, s1);
      }
    }
    // ---- gate * scale, causal mask, online softmax ----
    float esc[4];
    #pragma unroll
    for (int r = 0; r < 4; ++r) {
      const int q = q_base + lg * 4 + r;
      float g0 = cq[r] * ck0 + sq[r] * sk0;   // includes SCALE
      float g1 = cq[r] * ck1 + sq[r] * sk1;
      float v0 = s0[r] * g0;
      float v1 = s1[r] * g1;
      if (k0 + lr > q) v0 = -1e30f;
      if (k0 + lr + 16 > q) v1 = -1e30f;
      float tm = fmaxf(v0, v1);
      tm = fmaxf(tm, __shfl_xor(tm, 1));
      tm = fmaxf(tm, __shfl_xor(tm, 2));
      tm = fmaxf(tm, __shfl_xor(tm, 4));
      tm = fmaxf(tm, __shfl_xor(tm, 8));
      const float mn = fmaxf(m_run[r], tm);
      float e0 = __expf(v0 - mn);
      float e1 = __expf(v1 - mn);
      float ps = e0 + e1;
      ps += __shfl_xor(ps, 1);
      ps += __shfl_xor(ps, 2);
      ps += __shfl_xor(ps, 4);
      ps += __shfl_xor(ps, 8);
      esc[r] = __expf(m_run[r] - mn);
      l_run[r] = l_run[r] * esc[r] + ps;
      m_run[r] = mn;
      p_s[wid][lg * 4 + r][lr] = f2bf(e0);
      p_s[wid][lg * 4 + r][lr + 16] = f2bf(e1);
    }
    // rescale O
    #pragma unroll
    for (int n = 0; n < 4; ++n)
      #pragma unroll
      for (int r = 0; r < 4; ++r) o_acc[n][r] *= esc[r];
    // ---- PV: O += P(16x32) @ V(32x64) ----
    bf16x8 pa = *(const bf16x8*)&p_s[wid][lr][lg * 8];
    #pragma unroll
    for (int n = 0; n < 4; ++n) {
      bf16x8 vf = *(const bf16x8*)(VT + ((size_t)bh * 64 + n * 16 + lr) * T_ + k0 + lg * 8);
      o_acc[n] = mfma16(pa, vf, o_acc[n]);
    }
    // rotate key trig by delta angle (32 keys / GAMMA = 4)
    float t0 = ck0 * cd - sk0 * sd; sk0 = ck0 * sd + sk0 * cd; ck0 = t0;
    float t1 = ck1 * cd - sk1 * sd; sk1 = ck1 * sd + sk1 * cd; ck1 = t1;
  }
  // ---- epilogue: normalize, store fp32 (B,T,C) ----
  #pragma unroll
  for (int r = 0; r < 4; ++r) {
    const float linv = 1.0f / l_run[r];
    const int q = q_base + lg * 4 + r;
    float* Orow = O + ((size_t)b * T_ + q) * C_ + h * 64;
    #pragma unroll
    for (int n = 0; n < 4; ++n)
      Orow[n * 16 + lr] = o_acc[n][r] * linv;
  }
}

} // namespace

extern "C" void kernel_launch(void* const* d_in, const int* in_sizes, int n_in,
                              void* d_out, int out_size, void* d_ws, size_t ws_size,
                              hipStream_t stream) {
  const float* x  = (const float*)d_in[0];
  const float* Wq = (const float*)d_in[1];
  const float* Wk = (const float*)d_in[2];
  const float* Wv = (const float*)d_in[3];
  const float* Wo = (const float*)d_in[4];
  const float* th = (const float*)d_in[5];
  float* out = (float*)d_out;
  float* ws = (float*)d_ws;

  // workspace (72 MB):
  //   raw   fp32 [8,388,608]  : q_raw / k_raw, then V fp32 [0:4M) + attn-out [4M:8M)
  //   Qb    bf16 [8,388,608]  : packed (B,H,T,128)
  //   Kb    bf16 [8,388,608]
  //   vt    bf16 [4,194,304]  : (B,H,64,T)
  float* raw = ws;
  float* Vf  = raw;
  float* Ob  = raw + 4194304;
  ushort_t* Qb = (ushort_t*)(ws + 8388608);
  ushort_t* Kb = Qb + 8388608;
  ushort_t* vt = Kb + 8388608;

  dim3 blk(256);
  gemm_f32<<<dim3(2048 / BN, 4096 / BM), blk, 0, stream>>>(x, Wq, raw, 2048, 1024);
  qk_transform<<<16384, blk, 0, stream>>>(raw, Qb);
  gemm_f32<<<dim3(2048 / BN, 4096 / BM), blk, 0, stream>>>(x, Wk, raw, 2048, 1024);
  qk_transform<<<16384, blk, 0, stream>>>(raw, Kb);
  gemm_f32<<<dim3(1024 / BN, 4096 / BM), blk, 0, stream>>>(x, Wv, Vf, 1024, 1024);
  v_transpose<<<dim3(64, 32), blk, 0, stream>>>(Vf, vt);
  attn_mfma<<<dim3(32, 32), blk, 0, stream>>>(Qb, Kb, vt, th, Ob);
  gemm_f32<<<dim3(8, 32), blk, 0, stream>>>(Ob, Wo, out, 1024, 1024);
}

// Round 5
// 521.367 us; speedup vs baseline: 4.2729x; 1.9838x over previous
//
#include <hip/hip_runtime.h>
#include <cmath>

namespace {

constexpr int B_ = 2, T_ = 2048, C_ = 1024, H_ = 16;
constexpr float GAMMA_INV = 0.125f;   // 1/GAMMA
constexpr float SCALE = 0.125f;       // 1/sqrt(D), D=64

typedef __attribute__((ext_vector_type(8))) short bf16x8;
typedef __attribute__((ext_vector_type(4))) float f32x4;
typedef unsigned short ushort_t;

__device__ __forceinline__ ushort_t f2bf(float x) {
  union { float f; unsigned int u; } v; v.f = x;
  unsigned int r = (v.u + 0x7fffu + ((v.u >> 16) & 1u)) >> 16;
  return (ushort_t)r;
}

__device__ __forceinline__ f32x4 mfma16(bf16x8 a, bf16x8 b, f32x4 c) {
  return __builtin_amdgcn_mfma_f32_16x16x32_bf16(a, b, c, 0, 0, 0);
}

// ---------------- bf16 MFMA GEMM, register-staged LDS ----------------
// C(M,N) fp32 = A(M,K) bf16 row-major @ Bt(N,K)^T bf16 row-major
constexpr int GBM = 128, GBN = 128, GBK = 32;
constexpr int LDP = 40;   // padded row: 40 ushorts = 80 B (16B-aligned, 2-way banks)

__global__ __launch_bounds__(256) void gemm_bt(const ushort_t* __restrict__ A,
                                               const ushort_t* __restrict__ Bt,
                                               float* __restrict__ Cm,
                                               int N, int K) {
  __shared__ alignas(16) ushort_t As[GBM][LDP];
  __shared__ alignas(16) ushort_t Bs[GBN][LDP];
  const int tid = threadIdx.x;
  const int m0 = blockIdx.y * GBM, n0 = blockIdx.x * GBN;
  const int wv = tid >> 6;
  const int ln = tid & 63;
  const int lr = ln & 15, hi = ln >> 4;
  const int wr = wv >> 1, wc = wv & 1;

  // staging map: chunk id = tid + p*256 (p=0,1); row = id>>2, c8 = (id&3)*8
  const int sr0 = tid >> 2, sc0 = (tid & 3) * 8;       // p=0: rows 0..63
  const int sr1 = sr0 + 64;                             // p=1: rows 64..127
  const ushort_t* gA0 = A + (size_t)(m0 + sr0) * K + sc0;
  const ushort_t* gA1 = A + (size_t)(m0 + sr1) * K + sc0;
  const ushort_t* gB0 = Bt + (size_t)(n0 + sr0) * K + sc0;
  const ushort_t* gB1 = Bt + (size_t)(n0 + sr1) * K + sc0;

  f32x4 acc[4][4];
  #pragma unroll
  for (int m = 0; m < 4; ++m)
    #pragma unroll
    for (int n = 0; n < 4; ++n)
      #pragma unroll
      for (int r = 0; r < 4; ++r) acc[m][n][r] = 0.0f;

  for (int k0 = 0; k0 < K; k0 += GBK) {
    uint4 a0 = *(const uint4*)(gA0 + k0);
    uint4 a1 = *(const uint4*)(gA1 + k0);
    uint4 b0 = *(const uint4*)(gB0 + k0);
    uint4 b1 = *(const uint4*)(gB1 + k0);
    *(uint4*)&As[sr0][sc0] = a0;
    *(uint4*)&As[sr1][sc0] = a1;
    *(uint4*)&Bs[sr0][sc0] = b0;
    *(uint4*)&Bs[sr1][sc0] = b1;
    __syncthreads();
    bf16x8 af[4], bfr[4];
    #pragma unroll
    for (int m = 0; m < 4; ++m)
      af[m] = *(const bf16x8*)&As[wr * 64 + m * 16 + lr][hi * 8];
    #pragma unroll
    for (int n = 0; n < 4; ++n)
      bfr[n] = *(const bf16x8*)&Bs[wc * 64 + n * 16 + lr][hi * 8];
    #pragma unroll
    for (int m = 0; m < 4; ++m)
      #pragma unroll
      for (int n = 0; n < 4; ++n)
        acc[m][n] = mfma16(af[m], bfr[n], acc[m][n]);
    __syncthreads();
  }
  #pragma unroll
  for (int m = 0; m < 4; ++m) {
    #pragma unroll
    for (int r = 0; r < 4; ++r) {
      const int row = m0 + wr * 64 + m * 16 + hi * 4 + r;
      float* Crow = Cm + (size_t)row * N + n0 + wc * 64;
      #pragma unroll
      for (int n = 0; n < 4; ++n)
        Crow[n * 16 + lr] = acc[m][n][r];
    }
  }
}

// -------- fp32 -> bf16 convert (4 elems/thread) --------
__global__ __launch_bounds__(256) void f32_to_bf16(const float* __restrict__ in,
                                                   ushort_t* __restrict__ out) {
  const int i = (blockIdx.x * 256 + threadIdx.x) * 4;
  float4 a = *(const float4*)&in[i];
  uint2 p;
  p.x = (unsigned)f2bf(a.x) | ((unsigned)f2bf(a.y) << 16);
  p.y = (unsigned)f2bf(a.z) | ((unsigned)f2bf(a.w) << 16);
  *(uint2*)&out[i] = p;
}

// -------- W (K,N) fp32 -> Wt (N,K) bf16 --------
__global__ __launch_bounds__(256) void wt_bf16(const float* __restrict__ W,
                                               ushort_t* __restrict__ Wt,
                                               int K, int N) {
  __shared__ ushort_t t[32][33];
  const int k0 = blockIdx.y * 32, n0 = blockIdx.x * 32;
  const int i = threadIdx.x;
  const int r = i >> 3, c4 = (i & 7) * 4;
  float4 v = *(const float4*)&W[(size_t)(k0 + r) * N + n0 + c4];
  t[r][c4 + 0] = f2bf(v.x); t[r][c4 + 1] = f2bf(v.y);
  t[r][c4 + 2] = f2bf(v.z); t[r][c4 + 3] = f2bf(v.w);
  __syncthreads();
  ushort_t o0 = t[c4 + 0][r], o1 = t[c4 + 1][r], o2 = t[c4 + 2][r], o3 = t[c4 + 3][r];
  uint2 p;
  p.x = (unsigned)o0 | ((unsigned)o1 << 16);
  p.y = (unsigned)o2 | ((unsigned)o3 << 16);
  *(uint2*)&Wt[(size_t)(n0 + r) * K + k0 + c4] = p;
}

// -------- transform: raw (B,T,2C) fp32 -> packed (B,H,T,128) bf16 --------
__global__ __launch_bounds__(256) void qk_transform(const float* __restrict__ raw,
                                                    ushort_t* __restrict__ out) {
  const int idx = blockIdx.x * 256 + threadIdx.x;   // over B*T*C
  const int c = idx & (C_ - 1);
  const int bt = idx >> 10;
  const int t = bt & (T_ - 1);
  const int b = bt >> 11;
  const int h = c >> 6, d = c & 63;
  float amp = raw[(size_t)bt * 2048 + c];
  float ph  = raw[(size_t)bt * 2048 + 1024 + c];
  float sp = (amp > 20.f) ? amp : log1pf(expf(amp));
  float qc = sp * cosf(ph);
  float qs = sp * sinf(ph);
  size_t o = ((size_t)((b * H_ + h) * T_ + t)) * 128 + d;
  out[o] = f2bf(qc);
  out[o + 64] = f2bf(qs);
}

// -------- V (B,T,C) fp32 -> V^T (B,H,64,T) bf16 --------
__global__ __launch_bounds__(256) void v_transpose(const float* __restrict__ V,
                                                   ushort_t* __restrict__ VT) {
  const int bh = blockIdx.y;
  const int b = bh >> 4, h = bh & 15;
  const int t0 = blockIdx.x * 32;
  __shared__ ushort_t lds[32][72];
  const int i = threadIdx.x;
  {
    int r = i >> 3, d0 = (i & 7) * 8;
    const float* src = V + ((size_t)(b * T_) + t0 + r) * C_ + h * 64 + d0;
    float4 a = *(const float4*)src;
    float4 c = *(const float4*)(src + 4);
    lds[r][d0 + 0] = f2bf(a.x); lds[r][d0 + 1] = f2bf(a.y);
    lds[r][d0 + 2] = f2bf(a.z); lds[r][d0 + 3] = f2bf(a.w);
    lds[r][d0 + 4] = f2bf(c.x); lds[r][d0 + 5] = f2bf(c.y);
    lds[r][d0 + 6] = f2bf(c.z); lds[r][d0 + 7] = f2bf(c.w);
  }
  __syncthreads();
  {
    int d = i >> 2, tq = (i & 3) * 8;
    ushort_t tmp[8];
    #pragma unroll
    for (int j = 0; j < 8; ++j) tmp[j] = lds[tq + j][d];
    ulonglong2 pk;
    pk.x = (unsigned long long)tmp[0] | ((unsigned long long)tmp[1] << 16) |
           ((unsigned long long)tmp[2] << 32) | ((unsigned long long)tmp[3] << 48);
    pk.y = (unsigned long long)tmp[4] | ((unsigned long long)tmp[5] << 16) |
           ((unsigned long long)tmp[6] << 32) | ((unsigned long long)tmp[7] << 48);
    *(ulonglong2*)(VT + ((size_t)bh * 64 + d) * T_ + t0 + tq) = pk;
  }
}

// -------- flash attention, bf16 MFMA, moire gate --------
// Q,K: (B*H, T, 128) bf16; VT: (B*H, 64, T) bf16; O: (B,T,C) bf16
__global__ __launch_bounds__(256) void attn_mfma(const ushort_t* __restrict__ Q,
                                                 const ushort_t* __restrict__ K,
                                                 const ushort_t* __restrict__ VT,
                                                 const float* __restrict__ theta,
                                                 ushort_t* __restrict__ O) {
  const int bh = blockIdx.y;
  const int b = bh >> 4, h = bh & 15;
  const int wid = threadIdx.x >> 6, lane = threadIdx.x & 63;
  const int q_base = blockIdx.x * 64 + wid * 16;
  const int lr = lane & 15, lg = lane >> 4;
  __shared__ alignas(16) ushort_t p_s[4][16][40];

  const float th = theta[h];

  bf16x8 qf[4];
  {
    const ushort_t* Qrow = Q + ((size_t)bh * T_ + q_base + lr) * 128 + lg * 8;
    #pragma unroll
    for (int ks = 0; ks < 4; ++ks) qf[ks] = *(const bf16x8*)(Qrow + ks * 32);
  }

  float cq[4], sq[4];
  #pragma unroll
  for (int r = 0; r < 4; ++r) {
    float ang = th * (float)(q_base + lg * 4 + r) * GAMMA_INV;
    cq[r] = cosf(ang) * SCALE;
    sq[r] = sinf(ang) * SCALE;
  }
  float a0 = th * (float)lr * GAMMA_INV;
  float a1 = th * (float)(lr + 16) * GAMMA_INV;
  float ck0 = cosf(a0), sk0 = sinf(a0);
  float ck1 = cosf(a1), sk1 = sinf(a1);
  const float cd = cosf(th * 4.0f), sd = sinf(th * 4.0f);

  f32x4 o_acc[4];
  #pragma unroll
  for (int n = 0; n < 4; ++n)
    #pragma unroll
    for (int r = 0; r < 4; ++r) o_acc[n][r] = 0.0f;
  float m_run[4], l_run[4];
  #pragma unroll
  for (int r = 0; r < 4; ++r) { m_run[r] = -1e30f; l_run[r] = 0.0f; }

  const int nkt = ((q_base + 15) >> 5) + 1;
  for (int kt = 0; kt < nkt; ++kt) {
    const int k0 = kt * 32;
    f32x4 s0, s1;
    #pragma unroll
    for (int r = 0; r < 4; ++r) { s0[r] = 0.0f; s1[r] = 0.0f; }
    {
      const ushort_t* Krow0 = K + ((size_t)bh * T_ + k0 + lr) * 128 + lg * 8;
      const ushort_t* Krow1 = Krow0 + 16 * 128;
      #pragma unroll
      for (int ks = 0; ks < 4; ++ks) {
        bf16x8 kf0 = *(const bf16x8*)(Krow0 + ks * 32);
        bf16x8 kf1 = *(const bf16x8*)(Krow1 + ks * 32);
        s0 = mfma16(qf[ks], kf0, s0);
        s1 = mfma16(qf[ks], kf1, s1);
      }
    }
    float esc[4];
    #pragma unroll
    for (int r = 0; r < 4; ++r) {
      const int q = q_base + lg * 4 + r;
      float g0 = cq[r] * ck0 + sq[r] * sk0;
      float g1 = cq[r] * ck1 + sq[r] * sk1;
      float v0 = s0[r] * g0;
      float v1 = s1[r] * g1;
      if (k0 + lr > q) v0 = -1e30f;
      if (k0 + lr + 16 > q) v1 = -1e30f;
      float tm = fmaxf(v0, v1);
      tm = fmaxf(tm, __shfl_xor(tm, 1));
      tm = fmaxf(tm, __shfl_xor(tm, 2));
      tm = fmaxf(tm, __shfl_xor(tm, 4));
      tm = fmaxf(tm, __shfl_xor(tm, 8));
      const float mn = fmaxf(m_run[r], tm);
      float e0 = __expf(v0 - mn);
      float e1 = __expf(v1 - mn);
      float ps = e0 + e1;
      ps += __shfl_xor(ps, 1);
      ps += __shfl_xor(ps, 2);
      ps += __shfl_xor(ps, 4);
      ps += __shfl_xor(ps, 8);
      esc[r] = __expf(m_run[r] - mn);
      l_run[r] = l_run[r] * esc[r] + ps;
      m_run[r] = mn;
      p_s[wid][lg * 4 + r][lr] = f2bf(e0);
      p_s[wid][lg * 4 + r][lr + 16] = f2bf(e1);
    }
    #pragma unroll
    for (int n = 0; n < 4; ++n)
      #pragma unroll
      for (int r = 0; r < 4; ++r) o_acc[n][r] *= esc[r];
    bf16x8 pa = *(const bf16x8*)&p_s[wid][lr][lg * 8];
    #pragma unroll
    for (int n = 0; n < 4; ++n) {
      bf16x8 vf = *(const bf16x8*)(VT + ((size_t)bh * 64 + n * 16 + lr) * T_ + k0 + lg * 8);
      o_acc[n] = mfma16(pa, vf, o_acc[n]);
    }
    float t0 = ck0 * cd - sk0 * sd; sk0 = ck0 * sd + sk0 * cd; ck0 = t0;
    float t1 = ck1 * cd - sk1 * sd; sk1 = ck1 * sd + sk1 * cd; ck1 = t1;
  }
  #pragma unroll
  for (int r = 0; r < 4; ++r) {
    const float linv = 1.0f / l_run[r];
    const int q = q_base + lg * 4 + r;
    ushort_t* Orow = O + ((size_t)b * T_ + q) * C_ + h * 64;
    #pragma unroll
    for (int n = 0; n < 4; ++n)
      Orow[n * 16 + lr] = f2bf(o_acc[n][r] * linv);
  }
}

} // namespace

extern "C" void kernel_launch(void* const* d_in, const int* in_sizes, int n_in,
                              void* d_out, int out_size, void* d_ws, size_t ws_size,
                              hipStream_t stream) {
  const float* x  = (const float*)d_in[0];
  const float* Wq = (const float*)d_in[1];
  const float* Wk = (const float*)d_in[2];
  const float* Wv = (const float*)d_in[3];
  const float* Wo = (const float*)d_in[4];
  const float* th = (const float*)d_in[5];
  float* out = (float*)d_out;
  float* ws = (float*)d_ws;

  // ---- workspace layout (float offsets; total 22,020,096 floats = 88 MB) ----
  // SIZES (bf16 elems): Qb/Kb = B*H*T*128 = 8,388,608 (16 MB each!)
  //                     vt = Ob = 4,194,304 (8 MB);  xb = 4,194,304 (8 MB)
  // raw fp32 [0, 8388608): q_raw/k_raw (B*T,2048).
  //   After last qk_transform, raw is re-used: Vf fp32 [0, 4194304),
  //   Ob bf16 at float-offset 4194304 (spans [4194304, 6291456)),
  //   vt bf16 at float-offset 6291456 (spans [6291456, 8388608)).
  // Lifetimes: Vf written step5, read by v_transpose; vt written step5, read step6;
  //            Ob written step6, read step7. No overlap in time.
  float* raw = ws;
  float* Vf  = raw;
  ushort_t* Ob  = (ushort_t*)(ws + 4194304);
  ushort_t* vt  = (ushort_t*)(ws + 6291456);
  ushort_t* Qb  = (ushort_t*)(ws + 8388608);   // floats [ 8388608,12582912)
  ushort_t* Kb  = (ushort_t*)(ws + 12582912);  // floats [12582912,16777216)
  ushort_t* xb  = (ushort_t*)(ws + 16777216);  // floats [16777216,18874368)
  ushort_t* Wqt = (ushort_t*)(ws + 18874368);  // (2048,1024) bf16, 4 MB
  ushort_t* Wkt = (ushort_t*)(ws + 19922944);  // 4 MB
  ushort_t* Wvt = (ushort_t*)(ws + 20971520);  // (1024,1024) bf16, 2 MB
  ushort_t* Wot = (ushort_t*)(ws + 21495808);  // 2 MB

  dim3 blk(256);
  f32_to_bf16<<<4096, blk, 0, stream>>>(x, xb);
  wt_bf16<<<dim3(64, 32), blk, 0, stream>>>(Wq, Wqt, 1024, 2048);
  wt_bf16<<<dim3(64, 32), blk, 0, stream>>>(Wk, Wkt, 1024, 2048);
  wt_bf16<<<dim3(32, 32), blk, 0, stream>>>(Wv, Wvt, 1024, 1024);
  wt_bf16<<<dim3(32, 32), blk, 0, stream>>>(Wo, Wot, 1024, 1024);

  gemm_bt<<<dim3(16, 32), blk, 0, stream>>>(xb, Wqt, raw, 2048, 1024);
  qk_transform<<<16384, blk, 0, stream>>>(raw, Qb);
  gemm_bt<<<dim3(16, 32), blk, 0, stream>>>(xb, Wkt, raw, 2048, 1024);
  qk_transform<<<16384, blk, 0, stream>>>(raw, Kb);
  gemm_bt<<<dim3(8, 32), blk, 0, stream>>>(xb, Wvt, Vf, 1024, 1024);
  v_transpose<<<dim3(64, 32), blk, 0, stream>>>(Vf, vt);
  attn_mfma<<<dim3(32, 32), blk, 0, stream>>>(Qb, Kb, vt, th, Ob);
  gemm_bt<<<dim3(8, 32), blk, 0, stream>>>(Ob, Wot, out, 1024, 1024);
}